// Round 5
// baseline (232.661 us; speedup 1.0000x reference)
//
#include <hip/hip_runtime.h>

#define T_DIM 512
#define B_DIM 4096
#define L_DIM 4
#define LOG2E 1.44269504088896f
#define TWOLOG2E 2.88539008177793f      // 2*log2(e)
#define HALF_LN2 0.346573590279973f     // 1/(2*log2(e)) = ln(2)/2

typedef float f4 __attribute__((ext_vector_type(4)));

// DPP move with compile-time ctrl (bound_ctrl=1: OOB lanes read 0).
template <int CTRL>
__device__ __forceinline__ float dpp_mov(float v) {
  int r = __builtin_amdgcn_update_dpp(0, __builtin_bit_cast(int, v), CTRL, 0xf, 0xf, true);
  return __builtin_bit_cast(float, r);
}
template <int CTRL>
__device__ __forceinline__ float qp_add(float v) { return v + dpp_mov<CTRL>(v); }

// Async global->LDS DMA, 4B per lane: lane i's dword lands at ldst + 4*i.
// The DMA issue point is pinned in program order (side-effecting intrinsic),
// so the prefetch distance cannot be collapsed by scheduler heuristics —
// unlike R3/R4's VGPR rings.
__device__ __forceinline__ void dma4(const float* gsrc, float* ldst) {
  __builtin_amdgcn_global_load_lds(
      (const __attribute__((address_space(1))) void*)gsrc,
      (__attribute__((address_space(3))) void*)ldst, 4, 0, 0);
}

// Wave-private drain. Everything outstanding at each use was issued a full
// chunk (~2000 cy) earlier: chunk-m's 8 DMAs (issued mid-chunk m-1) and the
// batched FLUSH stores of chunk m-2 (issued at top of chunk m-1). Near-free.
#define WAITV0 asm volatile("s_waitcnt vmcnt(0)" ::: "memory")

// ---------------- gate-split layer-skewed fused LSTM -------------------------
// 256 blocks x 256 threads = 1024 waves (4 waves/CU, one per SIMD).
// lane = 16*c + 4*l + g: chain c (16-lane row), layer l, gate g.
// Skew: quad (c,l) is at time t = k - l; h_{l-1}(t) arrives via row_shr:4.
//
// R5: x staged through LDS by global_load_lds (wave-private double buffer,
// 2 x 8 slices x 256B per wave). The wave's 64 lanes map exactly onto one
// 256B x-slice (element index c*16+4l+g == lane), matching the DMA's
// uniform-base + lane*4 dest rule. Consumption: quad-broadcast ds_read_b128
// (4 lanes of a quad read the same 16B = chunk l of chain c) -> 4-fma dot +
// two row_ror butterflies. No VGPR prefetch ring exists for the scheduler
// to collapse — this is the structural fix for R3/R4's exposed-latency.
//
// Gates: one per lane (1 exp2 + 1 rcp); all four (i,f,g~,o) gathered with 4
// quad_perm reads so every lane holds valid state. Weights pre-scaled by
// -log2e (i,f,o) / +2log2e (g~) to feed exp2. Cell state tracked scaled:
// cse = 2log2e * c, so tanh's exp2 consumes it directly.
//
// Output h's are staged in named regs hs0..7 and flushed ONCE per chunk right
// AFTER the chunk-top wait — store-acks thus always have a full chunk to
// retire before the next vmcnt(0) sees them.
__global__ __launch_bounds__(256, 1) void lstm_fused(
    const float* __restrict__ x,      // [T,B,16]
    const float* __restrict__ Wih0,   // [4,16]
    const float* __restrict__ Wrest,  // [3,4]
    const float* __restrict__ Whh,    // [4,4]
    const float* __restrict__ bih, const float* __restrict__ bhh,
    float* __restrict__ out) {
  const int tid = threadIdx.x;
  const int lane = tid & 63;
  const int wid = tid >> 6;               // wave id in block, 0..3
  const int g = lane & 3;
  const int l = (lane >> 2) & 3;
  const int c = (lane >> 4) & 3;
  const int chain = blockIdx.x * 16 + wid * 4 + c;
  const bool l0 = (l == 0);

  __shared__ float sh[4096];              // 4 waves x 2 bufs x 8 slices x 64

  // gate scale: -log2e for sigmoid gates (i,f,o), +2log2e for tanh (g~).
  auto sg = [](int i) { return (i == 2) ? 2.0f * LOG2E : -LOG2E; };

  // recurrent weights for this lane's (l, g)
  const float whh  = sg(g) * Whh[l * 4 + g];
  const float wih  = l0 ? 0.f : sg(g) * Wrest[(l - 1) * 4 + g];
  const float base = l0 ? 0.f : sg(g) * (bih[l * 4 + g] + bhh[l * 4 + g]);
  // layer-0 GEMV weights: lane (c,l,g) holds gate g's weights for chunk l
  f4 wx;
  {
    const float s = sg(g);
    wx.x = s * Wih0[g * 16 + 4 * l + 0];
    wx.y = s * Wih0[g * 16 + 4 * l + 1];
    wx.z = s * Wih0[g * 16 + 4 * l + 2];
    wx.w = s * Wih0[g * 16 + 4 * l + 3];
  }
  // layer-0 bias, injected once per gate column (chunk l==0 lane)
  const float dinit = l0 ? sg(g) * (bih[g] + bhh[g]) : 0.f;
  // gate post-map: sigmoid lanes v = r; tanh lane v = 2log2e*(1-2r) (scaled).
  const float vm = (g == 2) ? -2.f * TWOLOG2E : 1.f;
  const float va = (g == 2) ? TWOLOG2E : 0.f;

  // per-lane global src base: lane's element of this wave's 256B x-slice.
  const float* __restrict__ xg = x + (size_t)blockIdx.x * 256 + wid * 64 + lane;
  float* __restrict__ po = out + chain;

  // LDS bases (floats): DMA dest is wave-uniform; read addr is per-quad.
  const int shw = wid * 1024;                       // this wave's 4KB region
  const int rdb = shw + c * 16 + 4 * l;             // + buf*512 + j*64

  float h = 0.f, cse = 0.f;
  float hs0, hs1, hs2, hs3, hs4, hs5, hs6, hs7;
  f4 X0, X1, X2, X3, X4, X5, X6, X7;

#define DMA8(B, t0)                                                         \
  do {                                                                      \
    const float* _g = xg + (size_t)(t0) * 65536;                            \
    float* _d = &sh[shw + (B) * 512];                                       \
    dma4(_g + 0 * 65536, _d + 0 * 64);                                      \
    dma4(_g + 1 * 65536, _d + 1 * 64);                                      \
    dma4(_g + 2 * 65536, _d + 2 * 64);                                      \
    dma4(_g + 3 * 65536, _d + 3 * 64);                                      \
    dma4(_g + 4 * 65536, _d + 4 * 64);                                      \
    dma4(_g + 5 * 65536, _d + 5 * 64);                                      \
    dma4(_g + 6 * 65536, _d + 6 * 64);                                      \
    dma4(_g + 7 * 65536, _d + 7 * 64);                                      \
  } while (0)

  // Quad-broadcast reads: 4 lanes of a quad read the same 16B (free), 16
  // distinct 16B addrs/wave -> 2-way bank aliasing (free per m136).
#define READ8(B)                                                            \
  do {                                                                      \
    X0 = *(const f4*)&sh[rdb + (B) * 512 + 0 * 64];                         \
    X1 = *(const f4*)&sh[rdb + (B) * 512 + 1 * 64];                         \
    X2 = *(const f4*)&sh[rdb + (B) * 512 + 2 * 64];                         \
    X3 = *(const f4*)&sh[rdb + (B) * 512 + 3 * 64];                         \
    X4 = *(const f4*)&sh[rdb + (B) * 512 + 4 * 64];                         \
    X5 = *(const f4*)&sh[rdb + (B) * 512 + 5 * 64];                         \
    X6 = *(const f4*)&sh[rdb + (B) * 512 + 6 * 64];                         \
    X7 = *(const f4*)&sh[rdb + (B) * 512 + 7 * 64];                         \
  } while (0)

  // layer-0 gate dot: pure VALU, no h dependence.
  auto dotD = [&](f4 xv) -> float {
    float p = fmaf(xv.x, wx.x, fmaf(xv.y, wx.y, fmaf(xv.z, wx.z, fmaf(xv.w, wx.w, dinit))));
    p = qp_add<0x124>(p);                  // row_ror:4
    p = qp_add<0x128>(p);                  // row_ror:8 -> full gate-g dot everywhere
    return p;
  };

  auto cellv = [&](int k, float D, bool guard) -> float {
    float hin = dpp_mov<0x114>(h);           // row_shr:4 -> h_{l-1}(t); 0 for l=0
    float pb = l0 ? D : base;
    float gate = fmaf(whh, h, fmaf(wih, hin, pb));

    float r = __builtin_amdgcn_rcpf(1.0f + __builtin_amdgcn_exp2f(gate));
    float v = fmaf(vm, r, va);               // lane g: i, f, 2log2e*g~, o

    float i_  = dpp_mov<0x00>(v);            // quad lane0: i
    float f_  = dpp_mov<0x55>(v);            // quad lane1: f
    float tgs = dpp_mov<0xAA>(v);            // quad lane2: 2log2e*g~
    float o_  = dpp_mov<0xFF>(v);            // quad lane3: o
    float cne = fmaf(f_, cse, i_ * tgs);     // scaled cell state, all lanes
    float tcn = fmaf(-2.0f,
        __builtin_amdgcn_rcpf(1.0f + __builtin_amdgcn_exp2f(cne)), 1.0f);
    float hm = o_ * tcn;                     // valid in ALL lanes

    if (guard) {
      const bool valid = (unsigned)(k - l) < (unsigned)T_DIM;
      cse = valid ? cne : cse;
      h   = valid ? hm : h;
    } else {
      cse = cne; h = hm;
    }
    return hm;
  };

#define CELLS8(k0, guard)                                                   \
  do {                                                                      \
    float D0_ = dotD(X0), D1_ = dotD(X1), D2_ = dotD(X2), D3_ = dotD(X3),   \
          D4_ = dotD(X4), D5_ = dotD(X5), D6_ = dotD(X6), D7_ = dotD(X7);   \
    hs0 = cellv((k0) + 0, D0_, guard);                                      \
    hs1 = cellv((k0) + 1, D1_, guard);                                      \
    hs2 = cellv((k0) + 2, D2_, guard);                                      \
    hs3 = cellv((k0) + 3, D3_, guard);                                      \
    hs4 = cellv((k0) + 4, D4_, guard);                                      \
    hs5 = cellv((k0) + 5, D5_, guard);                                      \
    hs6 = cellv((k0) + 6, D6_, guard);                                      \
    hs7 = cellv((k0) + 7, D7_, guard);                                      \
  } while (0)

  // Batched flush of chunk k0's staged h's (t = k0+j-3, j in [jlo,jhi],
  // compile-time range — all emitted t's are in-bounds by construction).
#define FLUSH(k0, jlo, jhi)                                                 \
  do {                                                                      \
    if (l == 3 && g == 0) {                                                 \
      if (0 >= (jlo) && 0 <= (jhi)) po[(size_t)((k0) + 0 - 3) * B_DIM] = hs0; \
      if (1 >= (jlo) && 1 <= (jhi)) po[(size_t)((k0) + 1 - 3) * B_DIM] = hs1; \
      if (2 >= (jlo) && 2 <= (jhi)) po[(size_t)((k0) + 2 - 3) * B_DIM] = hs2; \
      if (3 >= (jlo) && 3 <= (jhi)) po[(size_t)((k0) + 3 - 3) * B_DIM] = hs3; \
      if (4 >= (jlo) && 4 <= (jhi)) po[(size_t)((k0) + 4 - 3) * B_DIM] = hs4; \
      if (5 >= (jlo) && 5 <= (jhi)) po[(size_t)((k0) + 5 - 3) * B_DIM] = hs5; \
      if (6 >= (jlo) && 6 <= (jhi)) po[(size_t)((k0) + 6 - 3) * B_DIM] = hs6; \
      if (7 >= (jlo) && 7 <= (jhi)) po[(size_t)((k0) + 7 - 3) * B_DIM] = hs7; \
    }                                                                       \
  } while (0)

  // Schedule per chunk m: WAITV0 (drains chunk-m DMA + chunk-(m-2) stores,
  // both a full chunk old) -> FLUSH(m-1) -> READ8 -> DMA8(m+1) -> CELLS8(m).
  DMA8(0, 0);
  WAITV0;                                   // prologue: exposed once (~1us max)
  READ8(0);
  DMA8(1, 8);
  CELLS8(0, true);                          // warm-up k=0..7
  WAITV0; FLUSH(0, 3, 7);  READ8(1); DMA8(0, 16); CELLS8(8, false);
  WAITV0; FLUSH(8, 0, 7);  READ8(0); DMA8(1, 24); CELLS8(16, false);
#pragma unroll 1
  for (int n = 3; n < 63; n += 2) {
    WAITV0; FLUSH(8 * (n - 1), 0, 7); READ8(1); DMA8(0, 8 * (n + 1));
    CELLS8(8 * n, false);
    WAITV0; FLUSH(8 * n, 0, 7);       READ8(0); DMA8(1, 8 * (n + 2));
    CELLS8(8 * (n + 1), false);
  }
  // chunk 63 (k=504..511): its DMA (t=504 -> buf1) was issued at n=61.
  WAITV0; FLUSH(8 * 62, 0, 7); READ8(1);
  CELLS8(504, false);
  FLUSH(504, 0, 7);
  // drain (k=512..519): stale-but-finite X regs; guard freezes all state.
  CELLS8(512, true);
  FLUSH(512, 0, 2);                         // t=509..511

  // hn, cn: every lane of quad (c,l) holds h_l(T-1) and cse_l(T-1)
  if (g == 0) {
    po[(size_t)T_DIM * B_DIM + (size_t)l * B_DIM] = h;
    po[(size_t)T_DIM * B_DIM + (size_t)L_DIM * B_DIM + (size_t)l * B_DIM] =
        cse * HALF_LN2;                     // unscale once
  }
#undef DMA8
#undef READ8
#undef CELLS8
#undef FLUSH
}

extern "C" void kernel_launch(void* const* d_in, const int* in_sizes, int n_in,
                              void* d_out, int out_size, void* d_ws, size_t ws_size,
                              hipStream_t stream) {
  const float* x     = (const float*)d_in[0];
  const float* Wih0  = (const float*)d_in[1];
  const float* Wrest = (const float*)d_in[2];
  const float* Whh   = (const float*)d_in[3];
  const float* bih   = (const float*)d_in[4];
  const float* bhh   = (const float*)d_in[5];
  float* out = (float*)d_out;
  lstm_fused<<<B_DIM / 16, 256, 0, stream>>>(x, Wih0, Wrest, Whh, bih, bhh, out);
}